// Round 1
// baseline (342.360 us; speedup 1.0000x reference)
//
#include <hip/hip_runtime.h>
#include <hip/hip_bf16.h>

typedef float f32x4 __attribute__((ext_vector_type(4)));
typedef long i64;

#define FP8_MAX 448.0f

// ---------------- helpers ----------------

__device__ __forceinline__ void g2l16(const void* g, void* l) {
    __builtin_amdgcn_global_load_lds(
        (const __attribute__((address_space(1))) void*)g,
        (__attribute__((address_space(3))) void*)l,
        16, 0, 0);
}

// ---------------- kernels ----------------

__global__ void init_kernel(unsigned* amax) {
    amax[0] = 0u;
    amax[1] = 0u;
}

__global__ void amax_kernel(const float* __restrict__ src, size_t n, unsigned* __restrict__ out) {
    float m = 0.0f;
    size_t i0 = ((size_t)blockIdx.x * blockDim.x + threadIdx.x) * 4;
    size_t stride = (size_t)gridDim.x * blockDim.x * 4;
    for (size_t i = i0; i < n; i += stride) {
        float4 v = *(const float4*)(src + i);
        m = fmaxf(m, fmaxf(fmaxf(fabsf(v.x), fabsf(v.y)), fmaxf(fabsf(v.z), fabsf(v.w))));
    }
    // wave64 butterfly reduce
    #pragma unroll
    for (int off = 32; off > 0; off >>= 1)
        m = fmaxf(m, __shfl_xor(m, off));
    if ((threadIdx.x & 63) == 0)
        atomicMax(out, __float_as_uint(m));   // non-negative floats: uint order == float order
}

__global__ void scales_kernel(const unsigned* __restrict__ amax, float* __restrict__ sc) {
    float ax = __uint_as_float(amax[0]);
    float aw = __uint_as_float(amax[1]);
    float sx = FP8_MAX / (ax * 1.1f);
    sx = (ax == 0.0f) ? 1.0f : fminf(sx, 10000.0f);
    float sw = FP8_MAX / (aw * 1.1f);
    sw = (aw == 0.0f) ? 1.0f : fminf(sw, 10000.0f);
    sc[2] = sx;
    sc[3] = sw;
    sc[4] = 1.0f / sx;
    sc[5] = 1.0f / sw;
}

__device__ __forceinline__ float qclamp(float v, float s) {
    return fminf(fmaxf(v * s, -FP8_MAX), FP8_MAX);
}

__global__ void quant_kernel(const float* __restrict__ src, size_t n,
                             const float* __restrict__ scale_p,
                             unsigned char* __restrict__ dst) {
    const float s = *scale_p;
    size_t i0 = ((size_t)blockIdx.x * blockDim.x + threadIdx.x) * 8;
    size_t stride = (size_t)gridDim.x * blockDim.x * 8;
    for (size_t i = i0; i < n; i += stride) {
        float4 v0 = *(const float4*)(src + i);
        float4 v1 = *(const float4*)(src + i + 4);
        // v_cvt_pk_fp8_f32: RNE, saturating, OCP e4m3fn on gfx950
        int lo = __builtin_amdgcn_cvt_pk_fp8_f32(qclamp(v0.x, s), qclamp(v0.y, s), 0, false);
        lo = __builtin_amdgcn_cvt_pk_fp8_f32(qclamp(v0.z, s), qclamp(v0.w, s), lo, true);
        int hi = __builtin_amdgcn_cvt_pk_fp8_f32(qclamp(v1.x, s), qclamp(v1.y, s), 0, false);
        hi = __builtin_amdgcn_cvt_pk_fp8_f32(qclamp(v1.z, s), qclamp(v1.w, s), hi, true);
        uint2 p;
        p.x = (unsigned)lo;
        p.y = (unsigned)hi;
        *(uint2*)(dst + i) = p;
    }
}

// GEMM: out[m][n] = (sum_k xq[m][k]*wq[n][k]) * invx * invw + bias[n]
// 128x128 tile, BK=128 fp8 bytes, 4 waves in 2x2, each wave 64x64 via 4x4
// frags of mfma_f32_16x16x32_fp8_fp8. LDS 2x16KB single-buffered (m97 structure).
// Swizzle: physical byte p of row r stores logical kbyte p ^ ((r&7)<<4).
// 2-way bank aliasing on ds_read_b64 (free per m136).
#define BM 128
#define BN 128
#define BKB 128

__global__ __launch_bounds__(256, 2) void gemm_fp8_kernel(
    const unsigned char* __restrict__ Aq,   // [M][K] fp8
    const unsigned char* __restrict__ Bq,   // [N][K] fp8  (w is row-major [N][K] = B^T)
    const float* __restrict__ bias,
    const float* __restrict__ sc,
    float* __restrict__ out,
    int M, int N, int K) {
    __shared__ alignas(16) unsigned char sA[BM * BKB];
    __shared__ alignas(16) unsigned char sB[BN * BKB];

    const int tid = threadIdx.x;
    const int wave = tid >> 6;
    const int lane = tid & 63;
    const int nbn = N / BN;
    const int brow = (blockIdx.x / nbn) * BM;
    const int bcol = (blockIdx.x % nbn) * BN;
    const int wrow = (wave >> 1) * 64;
    const int wcol = (wave & 1) * 64;

    f32x4 acc[4][4] = {};

    const int frow = lane & 15;
    const int kgrp = lane >> 4;

    // staging geometry: thread t covers lds bytes [i*4096 + t*16, +16) for issue i
    const int so = tid * 16;

    for (int k0 = 0; k0 < K; k0 += BKB) {
        __syncthreads();   // previous compute done reading LDS
        #pragma unroll
        for (int i = 0; i < 4; ++i) {
            int oo = i * 4096 + so;
            int r = oo >> 7;                       // row in tile
            int cl = (oo & 127) ^ ((r & 7) << 4);  // pre-swizzled logical kbyte
            g2l16(Aq + (size_t)(brow + r) * K + k0 + cl, &sA[i * 4096 + wave * 1024]);
        }
        #pragma unroll
        for (int i = 0; i < 4; ++i) {
            int oo = i * 4096 + so;
            int r = oo >> 7;
            int cl = (oo & 127) ^ ((r & 7) << 4);
            g2l16(Bq + (size_t)(bcol + r) * K + k0 + cl, &sB[i * 4096 + wave * 1024]);
        }
        __syncthreads();   // compiler drains vmcnt(0) before barrier -> LDS ready

        #pragma unroll
        for (int kk = 0; kk < 4; ++kk) {
            i64 a[4], b[4];
            const int c = kk * 32 + kgrp * 8;
            #pragma unroll
            for (int m = 0; m < 4; ++m) {
                int row = wrow + m * 16 + frow;
                int addr = row * BKB + (c ^ ((row & 7) << 4));
                a[m] = *(const i64*)&sA[addr];
            }
            #pragma unroll
            for (int n = 0; n < 4; ++n) {
                int row = wcol + n * 16 + frow;
                int addr = row * BKB + (c ^ ((row & 7) << 4));
                b[n] = *(const i64*)&sB[addr];
            }
            #pragma unroll
            for (int m = 0; m < 4; ++m)
                #pragma unroll
                for (int n = 0; n < 4; ++n)
                    acc[m][n] = __builtin_amdgcn_mfma_f32_16x16x32_fp8_fp8(a[m], b[n], acc[m][n], 0, 0, 0);
        }
    }

    // epilogue: C/D layout col = lane&15, row = (lane>>4)*4 + j  (m89-verified, dtype-independent)
    const float invx = sc[4];
    const float invw = sc[5];
    #pragma unroll
    for (int n = 0; n < 4; ++n) {
        int col = bcol + wcol + n * 16 + frow;
        float bv = bias[col];
        #pragma unroll
        for (int m = 0; m < 4; ++m) {
            int row0 = brow + wrow + m * 16 + kgrp * 4;
            #pragma unroll
            for (int j = 0; j < 4; ++j) {
                out[(size_t)(row0 + j) * N + col] = acc[m][n][j] * invx * invw + bv;
            }
        }
    }
}

// ---------------- launch ----------------

extern "C" void kernel_launch(void* const* d_in, const int* in_sizes, int n_in,
                              void* d_out, int out_size, void* d_ws, size_t ws_size,
                              hipStream_t stream) {
    const float* x    = (const float*)d_in[0];
    const float* w    = (const float*)d_in[1];
    const float* bias = (const float*)d_in[2];
    float* out = (float*)d_out;

    const size_t nx = (size_t)in_sizes[0];
    const size_t nw = (size_t)in_sizes[1];
    const int N = in_sizes[2];
    const int K = (int)(nw / (size_t)N);
    const int M = (int)(nx / (size_t)K);

    unsigned* amax = (unsigned*)d_ws;
    float* sc = (float*)d_ws;
    unsigned char* xq = (unsigned char*)d_ws + 256;
    unsigned char* wq = xq + nx;

    init_kernel<<<1, 1, 0, stream>>>(amax);
    amax_kernel<<<1024, 256, 0, stream>>>(x, nx, amax + 0);
    amax_kernel<<<1024, 256, 0, stream>>>(w, nw, amax + 1);
    scales_kernel<<<1, 1, 0, stream>>>(amax, sc);
    quant_kernel<<<2048, 256, 0, stream>>>(x, nx, sc + 2, xq);
    quant_kernel<<<1024, 256, 0, stream>>>(w, nw, sc + 3, wq);

    dim3 grid((M / BM) * (N / BN));
    gemm_fp8_kernel<<<grid, 256, 0, stream>>>(xq, wq, bias, sc, out, M, N, K);
}

// Round 2
// 295.237 us; speedup vs baseline: 1.1596x; 1.1596x over previous
//
#include <hip/hip_runtime.h>
#include <hip/hip_bf16.h>

typedef float f32x16 __attribute__((ext_vector_type(16)));
typedef int   i32x8  __attribute__((ext_vector_type(8)));
typedef int   i32x4  __attribute__((ext_vector_type(4)));

#define FP8_MAX 448.0f

// ---------------- helpers ----------------

__device__ __forceinline__ void g2l16(const void* g, void* l) {
    __builtin_amdgcn_global_load_lds(
        (const __attribute__((address_space(1))) void*)g,
        (__attribute__((address_space(3))) void*)l,
        16, 0, 0);
}

__device__ __forceinline__ float scale_from(float amax) {
    float s = FP8_MAX / (amax * 1.1f);
    return (amax == 0.0f) ? 1.0f : fminf(s, 10000.0f);
}

// ---------------- preprocessing ----------------

__global__ void init_kernel(unsigned* amax) {
    amax[0] = 0u;
    amax[1] = 0u;
}

__global__ void amax_fused_kernel(const float* __restrict__ x, size_t nx,
                                  const float* __restrict__ w, size_t nw,
                                  unsigned* __restrict__ amax, int xblocks) {
    const float* src;
    size_t n;
    unsigned* out;
    int bid, nb;
    if ((int)blockIdx.x < xblocks) {
        src = x; n = nx; out = amax; bid = blockIdx.x; nb = xblocks;
    } else {
        src = w; n = nw; out = amax + 1; bid = blockIdx.x - xblocks; nb = gridDim.x - xblocks;
    }
    float m = 0.0f;
    size_t i0 = ((size_t)bid * blockDim.x + threadIdx.x) * 4;
    size_t stride = (size_t)nb * blockDim.x * 4;
    for (size_t i = i0; i < n; i += stride) {
        float4 v = *(const float4*)(src + i);
        m = fmaxf(m, fmaxf(fmaxf(fabsf(v.x), fabsf(v.y)), fmaxf(fabsf(v.z), fabsf(v.w))));
    }
    #pragma unroll
    for (int off = 32; off > 0; off >>= 1)
        m = fmaxf(m, __shfl_xor(m, off));
    if ((threadIdx.x & 63) == 0)
        atomicMax(out, __float_as_uint(m));   // non-negative: uint order == float order
}

__device__ __forceinline__ float qclamp(float v, float s) {
    return fminf(fmaxf(v * s, -FP8_MAX), FP8_MAX);
}

__global__ void quant_fused_kernel(const float* __restrict__ x, size_t nx,
                                   const float* __restrict__ w, size_t nw,
                                   const unsigned* __restrict__ amax,
                                   unsigned char* __restrict__ xq,
                                   unsigned char* __restrict__ wq, int xblocks) {
    const float* src;
    size_t n;
    unsigned char* dst;
    int bid, nb, sel;
    if ((int)blockIdx.x < xblocks) {
        src = x; n = nx; dst = xq; bid = blockIdx.x; nb = xblocks; sel = 0;
    } else {
        src = w; n = nw; dst = wq; bid = blockIdx.x - xblocks; nb = gridDim.x - xblocks; sel = 1;
    }
    const float s = scale_from(__uint_as_float(amax[sel]));
    size_t i0 = ((size_t)bid * blockDim.x + threadIdx.x) * 8;
    size_t stride = (size_t)nb * blockDim.x * 8;
    for (size_t i = i0; i < n; i += stride) {
        float4 v0 = *(const float4*)(src + i);
        float4 v1 = *(const float4*)(src + i + 4);
        int lo = __builtin_amdgcn_cvt_pk_fp8_f32(qclamp(v0.x, s), qclamp(v0.y, s), 0, false);
        lo = __builtin_amdgcn_cvt_pk_fp8_f32(qclamp(v0.z, s), qclamp(v0.w, s), lo, true);
        int hi = __builtin_amdgcn_cvt_pk_fp8_f32(qclamp(v1.x, s), qclamp(v1.y, s), 0, false);
        hi = __builtin_amdgcn_cvt_pk_fp8_f32(qclamp(v1.z, s), qclamp(v1.w, s), hi, true);
        uint2 p;
        p.x = (unsigned)lo;
        p.y = (unsigned)hi;
        *(uint2*)(dst + i) = p;
    }
}

// ---------------- GEMM ----------------
// out[m][n] = (sum_k xq[m][k]*wq[n][k]) * invx * invw + bias[n]
// Block tile 128x256 (A-rows x B-rows), BK = 128 fp8 bytes.
// 4 waves in 2x2; wave tile 64x128 = 2x4 frags of 32x32.
// MFMA: mfma_scale_f32_32x32x64_f8f6f4 with unit scales (e8m0 0x7F = 1.0)
//   -> identical math to plain fp8 at 2.27x the MFMA rate (m148 path).
// LDS swizzle: physical 16B chunk = logical chunk ^ ((row&7)<<4), both-sides
// (pre-swizzled global source on stage, swizzled ds_read addr) per rule #21.
#define BM 128
#define BN 256
#define BKB 128

__global__ __launch_bounds__(256, 2) void gemm_fp8_kernel(
    const unsigned char* __restrict__ Aq,   // [M][K] fp8
    const unsigned char* __restrict__ Bq,   // [N][K] fp8 (w row-major = B^T)
    const float* __restrict__ bias,
    const unsigned* __restrict__ amax,
    float* __restrict__ out,
    int M, int N, int K) {
    __shared__ alignas(16) unsigned char sA[BM * BKB];   // 16 KB
    __shared__ alignas(16) unsigned char sB[BN * BKB];   // 32 KB

    const int tid = threadIdx.x;
    const int wave = tid >> 6;
    const int lane = tid & 63;
    const int nbn = N / BN;
    const int brow = (blockIdx.x / nbn) * BM;
    const int bcol = (blockIdx.x % nbn) * BN;
    const int wrow = (wave >> 1) * 64;    // 0 or 64
    const int wcol = (wave & 1) * 128;    // 0 or 128

    f32x16 acc[2][4] = {};

    const int r31 = lane & 31;
    const int half = lane >> 5;
    const int so = tid * 16;

    union AB { i32x8 v8; i32x4 v4[2]; };

    for (int k0 = 0; k0 < K; k0 += BKB) {
        __syncthreads();   // previous compute done reading LDS
        // stage A: 16 KB, 4 issues; dest = wave-uniform base + lane*16
        #pragma unroll
        for (int i = 0; i < 4; ++i) {
            int oo = i * 4096 + so;
            int r = oo >> 7;
            int cl = (oo & 127) ^ ((r & 7) << 4);   // pre-swizzled source column
            g2l16(Aq + (size_t)(brow + r) * K + k0 + cl, &sA[i * 4096 + wave * 1024]);
        }
        // stage B: 32 KB, 8 issues
        #pragma unroll
        for (int i = 0; i < 8; ++i) {
            int oo = i * 4096 + so;
            int r = oo >> 7;
            int cl = (oo & 127) ^ ((r & 7) << 4);
            g2l16(Bq + (size_t)(bcol + r) * K + k0 + cl, &sB[i * 4096 + wave * 1024]);
        }
        __syncthreads();   // compiler drains vmcnt(0) before barrier

        #pragma unroll
        for (int ks = 0; ks < 2; ++ks) {
            const int kb = ks * 64 + half * 32;   // this lane's 32 k-bytes
            AB a[2], b[4];
            #pragma unroll
            for (int m = 0; m < 2; ++m) {
                int row = wrow + m * 32 + r31;
                int base = row * BKB;
                int sw = (row & 7) << 4;
                a[m].v4[0] = *(const i32x4*)&sA[base + (kb ^ sw)];
                a[m].v4[1] = *(const i32x4*)&sA[base + ((kb + 16) ^ sw)];
            }
            #pragma unroll
            for (int n = 0; n < 4; ++n) {
                int row = wcol + n * 32 + r31;
                int base = row * BKB;
                int sw = (row & 7) << 4;
                b[n].v4[0] = *(const i32x4*)&sB[base + (kb ^ sw)];
                b[n].v4[1] = *(const i32x4*)&sB[base + ((kb + 16) ^ sw)];
            }
            #pragma unroll
            for (int m = 0; m < 2; ++m)
                #pragma unroll
                for (int n = 0; n < 4; ++n)
                    acc[m][n] = __builtin_amdgcn_mfma_scale_f32_32x32x64_f8f6f4(
                        a[m].v8, b[n].v8, acc[m][n],
                        0, 0,                 // cbsz=fp8(e4m3), blgp=fp8(e4m3)
                        0, 0x7f7f7f7f,        // scale_a opsel, scale_a = 1.0
                        0, 0x7f7f7f7f);       // scale_b opsel, scale_b = 1.0
        }
    }

    // epilogue: 32x32 C/D layout (m74/m101, dtype-independent):
    // col = lane&31, row = (reg&3) + 8*(reg>>2) + 4*(lane>>5)
    const float invx = 1.0f / scale_from(__uint_as_float(amax[0]));
    const float invw = 1.0f / scale_from(__uint_as_float(amax[1]));
    #pragma unroll
    for (int n = 0; n < 4; ++n) {
        int col = bcol + wcol + n * 32 + r31;
        float bv = bias[col];
        #pragma unroll
        for (int m = 0; m < 2; ++m) {
            int rbase = brow + wrow + m * 32 + half * 4;
            #pragma unroll
            for (int r = 0; r < 16; ++r) {
                int row = rbase + (r & 3) + 8 * (r >> 2);
                out[(size_t)row * N + col] = acc[m][n][r] * invx * invw + bv;
            }
        }
    }
}

// ---------------- launch ----------------

extern "C" void kernel_launch(void* const* d_in, const int* in_sizes, int n_in,
                              void* d_out, int out_size, void* d_ws, size_t ws_size,
                              hipStream_t stream) {
    const float* x    = (const float*)d_in[0];
    const float* w    = (const float*)d_in[1];
    const float* bias = (const float*)d_in[2];
    float* out = (float*)d_out;

    const size_t nx = (size_t)in_sizes[0];
    const size_t nw = (size_t)in_sizes[1];
    const int N = in_sizes[2];
    const int K = (int)(nw / (size_t)N);
    const int M = (int)(nx / (size_t)K);

    unsigned* amax = (unsigned*)d_ws;
    unsigned char* xq = (unsigned char*)d_ws + 256;
    unsigned char* wq = xq + nx;

    const int TOTB = 2048;
    int xb = (int)((double)TOTB * (double)nx / (double)(nx + nw));
    if (xb < 1) xb = 1;
    if (xb > TOTB - 1) xb = TOTB - 1;

    init_kernel<<<1, 1, 0, stream>>>(amax);
    amax_fused_kernel<<<TOTB, 256, 0, stream>>>(x, nx, w, nw, amax, xb);
    quant_fused_kernel<<<TOTB, 256, 0, stream>>>(x, nx, w, nw, amax, xq, wq, xb);

    dim3 grid((M / BM) * (N / BN));
    gemm_fp8_kernel<<<grid, 256, 0, stream>>>(xq, wq, bias, amax, out, M, N, K);
}

// Round 3
// 216.999 us; speedup vs baseline: 1.5777x; 1.3605x over previous
//
#include <hip/hip_runtime.h>
#include <hip/hip_bf16.h>

typedef float f32x16 __attribute__((ext_vector_type(16)));
typedef int   i32x8  __attribute__((ext_vector_type(8)));
typedef int   i32x4  __attribute__((ext_vector_type(4)));

#define FP8_MAX 448.0f

// ---------------- helpers ----------------

__device__ __forceinline__ void g2l16(const void* g, void* l) {
    __builtin_amdgcn_global_load_lds(
        (const __attribute__((address_space(1))) void*)g,
        (__attribute__((address_space(3))) void*)l,
        16, 0, 0);
}

__device__ __forceinline__ float scale_from(float amax) {
    float s = FP8_MAX / (amax * 1.1f);
    return (amax == 0.0f) ? 1.0f : fminf(s, 10000.0f);
}

// ---------------- preprocessing ----------------

__global__ void init_kernel(unsigned* amax) {
    amax[0] = 0u;
    amax[1] = 0u;
}

// Latency fix: 8 independent float4 loads in flight per thread per iteration
// (round-2 version had 1 dependent load -> 1.27 TB/s effective; this is the
// Guideline-7 ILP fix).
__global__ void amax_fused_kernel(const float* __restrict__ x, size_t nx,
                                  const float* __restrict__ w, size_t nw,
                                  unsigned* __restrict__ amax, int xblocks) {
    const float* src;
    size_t n;
    unsigned* out;
    int bid, nb;
    if ((int)blockIdx.x < xblocks) {
        src = x; n = nx; out = amax; bid = blockIdx.x; nb = xblocks;
    } else {
        src = w; n = nw; out = amax + 1; bid = blockIdx.x - xblocks; nb = gridDim.x - xblocks;
    }
    float m = 0.0f;
    const size_t ustep = (size_t)blockDim.x * 4;         // floats per u-step (coalesced 1KB/wave)
    const size_t chunkf = ustep * 8;                     // floats per block-iter
    size_t base = (size_t)bid * chunkf + (size_t)threadIdx.x * 4;
    const size_t gstride = (size_t)nb * chunkf;
    for (; base < n; base += gstride) {
        float4 v[8];
        #pragma unroll
        for (int u = 0; u < 8; ++u) {
            size_t idx = base + (size_t)u * ustep;
            float4 vv = {0.0f, 0.0f, 0.0f, 0.0f};
            if (idx < n) vv = *(const float4*)(src + idx);   // n%4==0: full float4 valid
            v[u] = vv;
        }
        #pragma unroll
        for (int u = 0; u < 8; ++u)
            m = fmaxf(m, fmaxf(fmaxf(fabsf(v[u].x), fabsf(v[u].y)),
                               fmaxf(fabsf(v[u].z), fabsf(v[u].w))));
    }
    #pragma unroll
    for (int off = 32; off > 0; off >>= 1)
        m = fmaxf(m, __shfl_xor(m, off));
    __shared__ float sm[4];
    if ((threadIdx.x & 63) == 0) sm[threadIdx.x >> 6] = m;
    __syncthreads();
    if (threadIdx.x == 0) {
        float mm = fmaxf(fmaxf(sm[0], sm[1]), fmaxf(sm[2], sm[3]));
        atomicMax(out, __float_as_uint(mm));   // non-negative: uint order == float order
    }
}

__device__ __forceinline__ float qclamp(float v, float s) {
    return fminf(fmaxf(v * s, -FP8_MAX), FP8_MAX);
}

__global__ void quant_fused_kernel(const float* __restrict__ x, size_t nx,
                                   const float* __restrict__ w, size_t nw,
                                   const unsigned* __restrict__ amax,
                                   unsigned char* __restrict__ xq,
                                   unsigned char* __restrict__ wq, int xblocks) {
    const float* src;
    size_t n;
    unsigned char* dst;
    int bid, nb, sel;
    if ((int)blockIdx.x < xblocks) {
        src = x; n = nx; dst = xq; bid = blockIdx.x; nb = xblocks; sel = 0;
    } else {
        src = w; n = nw; dst = wq; bid = blockIdx.x - xblocks; nb = gridDim.x - xblocks; sel = 1;
    }
    const float s = scale_from(__uint_as_float(amax[sel]));
    const size_t ustep = (size_t)blockDim.x * 4;         // floats per u-step
    const size_t chunkf = ustep * 4;                     // 4 independent load/store pairs
    size_t base = (size_t)bid * chunkf + (size_t)threadIdx.x * 4;
    const size_t gstride = (size_t)nb * chunkf;
    for (; base < n; base += gstride) {
        float4 v[4];
        bool ok[4];
        #pragma unroll
        for (int u = 0; u < 4; ++u) {
            size_t idx = base + (size_t)u * ustep;
            ok[u] = idx < n;
            float4 vv = {0.0f, 0.0f, 0.0f, 0.0f};
            if (ok[u]) vv = *(const float4*)(src + idx);
            v[u] = vv;
        }
        #pragma unroll
        for (int u = 0; u < 4; ++u) {
            if (ok[u]) {
                int p = __builtin_amdgcn_cvt_pk_fp8_f32(qclamp(v[u].x, s), qclamp(v[u].y, s), 0, false);
                p = __builtin_amdgcn_cvt_pk_fp8_f32(qclamp(v[u].z, s), qclamp(v[u].w, s), p, true);
                *(unsigned*)(dst + base + (size_t)u * ustep) = (unsigned)p;
            }
        }
    }
}

// ---------------- GEMM (unchanged from round 2) ----------------
// out[m][n] = (sum_k xq[m][k]*wq[n][k]) * invx * invw + bias[n]
// Block tile 128x256, BK=128B; 4 waves 2x2; wave tile 64x128 = 2x4 frags 32x32.
// mfma_scale_f32_32x32x64_f8f6f4 with unit scales (e8m0 0x7F=1.0): identical
// math to plain fp8 at 2.27x the MFMA rate (m148 path).
#define BM 128
#define BN 256
#define BKB 128

__global__ __launch_bounds__(256, 2) void gemm_fp8_kernel(
    const unsigned char* __restrict__ Aq,
    const unsigned char* __restrict__ Bq,
    const float* __restrict__ bias,
    const unsigned* __restrict__ amax,
    float* __restrict__ out,
    int M, int N, int K) {
    __shared__ alignas(16) unsigned char sA[BM * BKB];
    __shared__ alignas(16) unsigned char sB[BN * BKB];

    const int tid = threadIdx.x;
    const int wave = tid >> 6;
    const int lane = tid & 63;
    const int nbn = N / BN;
    const int brow = (blockIdx.x / nbn) * BM;
    const int bcol = (blockIdx.x % nbn) * BN;
    const int wrow = (wave >> 1) * 64;
    const int wcol = (wave & 1) * 128;

    f32x16 acc[2][4] = {};

    const int r31 = lane & 31;
    const int half = lane >> 5;
    const int so = tid * 16;

    union AB { i32x8 v8; i32x4 v4[2]; };

    for (int k0 = 0; k0 < K; k0 += BKB) {
        __syncthreads();
        #pragma unroll
        for (int i = 0; i < 4; ++i) {
            int oo = i * 4096 + so;
            int r = oo >> 7;
            int cl = (oo & 127) ^ ((r & 7) << 4);
            g2l16(Aq + (size_t)(brow + r) * K + k0 + cl, &sA[i * 4096 + wave * 1024]);
        }
        #pragma unroll
        for (int i = 0; i < 8; ++i) {
            int oo = i * 4096 + so;
            int r = oo >> 7;
            int cl = (oo & 127) ^ ((r & 7) << 4);
            g2l16(Bq + (size_t)(bcol + r) * K + k0 + cl, &sB[i * 4096 + wave * 1024]);
        }
        __syncthreads();

        #pragma unroll
        for (int ks = 0; ks < 2; ++ks) {
            const int kb = ks * 64 + half * 32;
            AB a[2], b[4];
            #pragma unroll
            for (int m = 0; m < 2; ++m) {
                int row = wrow + m * 32 + r31;
                int bse = row * BKB;
                int sw = (row & 7) << 4;
                a[m].v4[0] = *(const i32x4*)&sA[bse + (kb ^ sw)];
                a[m].v4[1] = *(const i32x4*)&sA[bse + ((kb + 16) ^ sw)];
            }
            #pragma unroll
            for (int n = 0; n < 4; ++n) {
                int row = wcol + n * 32 + r31;
                int bse = row * BKB;
                int sw = (row & 7) << 4;
                b[n].v4[0] = *(const i32x4*)&sB[bse + (kb ^ sw)];
                b[n].v4[1] = *(const i32x4*)&sB[bse + ((kb + 16) ^ sw)];
            }
            #pragma unroll
            for (int m = 0; m < 2; ++m)
                #pragma unroll
                for (int n = 0; n < 4; ++n)
                    acc[m][n] = __builtin_amdgcn_mfma_scale_f32_32x32x64_f8f6f4(
                        a[m].v8, b[n].v8, acc[m][n],
                        0, 0, 0, 0x7f7f7f7f, 0, 0x7f7f7f7f);
        }
    }

    const float invx = 1.0f / scale_from(__uint_as_float(amax[0]));
    const float invw = 1.0f / scale_from(__uint_as_float(amax[1]));
    #pragma unroll
    for (int n = 0; n < 4; ++n) {
        int col = bcol + wcol + n * 32 + r31;
        float bv = bias[col];
        #pragma unroll
        for (int m = 0; m < 2; ++m) {
            int rbase = brow + wrow + m * 32 + half * 4;
            #pragma unroll
            for (int r = 0; r < 16; ++r) {
                int row = rbase + (r & 3) + 8 * (r >> 2);
                out[(size_t)row * N + col] = acc[m][n][r] * invx * invw + bv;
            }
        }
    }
}

// ---------------- launch ----------------

extern "C" void kernel_launch(void* const* d_in, const int* in_sizes, int n_in,
                              void* d_out, int out_size, void* d_ws, size_t ws_size,
                              hipStream_t stream) {
    const float* x    = (const float*)d_in[0];
    const float* w    = (const float*)d_in[1];
    const float* bias = (const float*)d_in[2];
    float* out = (float*)d_out;

    const size_t nx = (size_t)in_sizes[0];
    const size_t nw = (size_t)in_sizes[1];
    const int N = in_sizes[2];
    const int K = (int)(nw / (size_t)N);
    const int M = (int)(nx / (size_t)K);

    unsigned* amax = (unsigned*)d_ws;
    unsigned char* xq = (unsigned char*)d_ws + 256;
    unsigned char* wq = xq + nx;

    const int TOTB = 2048;
    int xb = (int)((double)TOTB * (double)nx / (double)(nx + nw));
    if (xb < 1) xb = 1;
    if (xb > TOTB - 1) xb = TOTB - 1;

    init_kernel<<<1, 1, 0, stream>>>(amax);
    amax_fused_kernel<<<TOTB, 256, 0, stream>>>(x, nx, w, nw, amax, xb);
    quant_fused_kernel<<<TOTB, 256, 0, stream>>>(x, nx, w, nw, amax, xq, wq, xb);

    dim3 grid((M / BM) * (N / BN));
    gemm_fp8_kernel<<<grid, 256, 0, stream>>>(xq, wq, bias, amax, out, M, N, K);
}